// Round 7
// baseline (220.423 us; speedup 1.0000x reference)
//
#include <hip/hip_runtime.h>

// Problem constants (from reference):
//   B=4, T=16, H=32, D=128, L=4096, HALF=64
// Inputs (setup_inputs order):
//   0: k_new  [B,T,H,D]  f32
//   1: v_new  [B,T,H,D]  f32
//   2: cos    [L,HALF]   f32
//   3: sin    [L,HALF]   f32
//   4: cache_k [B,L,H,D] f32
//   5: cache_v [B,L,H,D] f32
//   6: positions [B,T]   i32
// Output: [2, B, L, H, D] f32 — stack(out_k, out_v)

#define B 4
#define T 16
#define H 32
#define D 128
#define L 4096
#define HALF 64

typedef float f32x4 __attribute__((ext_vector_type(4)));

// ---------------------------------------------------------------------------
// Batched copy, depth 16, NO nontemporal (R6 A/B isolated nt as suspect):
// each block owns a contiguous 4096-float4 (64 KiB) chunk of the flat
// [cache_k ; cache_v] space. Each thread issues 16 independent dwordx4
// loads (256 B in flight), then 16 stores — long unidirectional bursts.
// Chunks never straddle the k/v boundary (n4 % 4096 == 0).
// ---------------------------------------------------------------------------
#define PER_THREAD 16
#define CHUNK (256 * PER_THREAD)   // 4096 float4s = 64 KiB per block

__global__ __launch_bounds__(256) void copy_caches_batched(
    const f32x4* __restrict__ cache_k,
    const f32x4* __restrict__ cache_v,
    f32x4* __restrict__ out,
    long n4) {
    const long flat0 = (long)blockIdx.x * CHUNK;           // block's first float4
    const bool second = flat0 >= n4;                        // block-uniform
    const f32x4* __restrict__ src = second ? cache_v : cache_k;
    const long srcoff = second ? (flat0 - n4) : flat0;

    const int t = threadIdx.x;
    f32x4 r[PER_THREAD];
#pragma unroll
    for (int j = 0; j < PER_THREAD; ++j)
        r[j] = src[srcoff + t + j * 256];
#pragma unroll
    for (int j = 0; j < PER_THREAD; ++j)
        out[flat0 + t + j * 256] = r[j];
}

// ---------------------------------------------------------------------------
// RoPE-rotate k_new and scatter k_rot / v_new into the output at the row
// given by positions[b,t]. One thread per interleaved pair. Runs AFTER the
// bulk copy on the same stream, overwriting the 64 target rows.
// ---------------------------------------------------------------------------
__global__ void rope_scatter(const float* __restrict__ k_new,
                             const float* __restrict__ v_new,
                             const float* __restrict__ cos_t,
                             const float* __restrict__ sin_t,
                             const int* __restrict__ positions,
                             float* __restrict__ out_k,
                             float* __restrict__ out_v) {
    int idx = blockIdx.x * blockDim.x + threadIdx.x;   // [0, B*T*H*HALF)
    int p  = idx & (HALF - 1);          // pair index within head dim
    int h  = (idx >> 6) & (H - 1);      // head
    int bt = idx >> 11;                 // b*T + t
    int b  = bt >> 4;                   // /T (T=16)

    int pos = positions[bt];

    const float2 kv = *(const float2*)(k_new + (size_t)idx * 2);
    const float2 vv = *(const float2*)(v_new + (size_t)idx * 2);
    float c = cos_t[pos * HALF + p];
    float s = sin_t[pos * HALF + p];

    float2 kr;
    kr.x = kv.x * c - kv.y * s;
    kr.y = kv.x * s + kv.y * c;

    size_t dst = (((size_t)b * L + pos) * H + h) * (size_t)D + 2 * (size_t)p;
    *(float2*)(out_k + dst) = kr;
    *(float2*)(out_v + dst) = vv;
}

extern "C" void kernel_launch(void* const* d_in, const int* in_sizes, int n_in,
                              void* d_out, int out_size, void* d_ws, size_t ws_size,
                              hipStream_t stream) {
    const float* k_new  = (const float*)d_in[0];
    const float* v_new  = (const float*)d_in[1];
    const float* cos_t  = (const float*)d_in[2];
    const float* sin_t  = (const float*)d_in[3];
    const f32x4* ck     = (const f32x4*)d_in[4];
    const f32x4* cv     = (const f32x4*)d_in[5];
    const int* positions = (const int*)d_in[6];

    float* out = (float*)d_out;
    const long cache_elems = (long)B * L * H * D;   // 67,108,864 floats
    const long n4 = cache_elems / 4;                // 16,777,216 float4s per cache

    // 2 * n4 / CHUNK = 8192 blocks, 256 threads, 16 float4s each, one shot.
    const int nblocks = (int)(2 * n4 / CHUNK);
    copy_caches_batched<<<nblocks, 256, 0, stream>>>(ck, cv, (f32x4*)out, n4);

    // Scatter: B*T*H*HALF = 131072 threads -> 512 blocks x 256.
    const int n_pairs = B * T * H * HALF;
    rope_scatter<<<n_pairs / 256, 256, 0, stream>>>(
        k_new, v_new, cos_t, sin_t, positions,
        out, out + cache_elems);
}

// Round 8
// 174.035 us; speedup vs baseline: 1.2665x; 1.2665x over previous
//
#include <hip/hip_runtime.h>

// Problem constants (from reference):
//   B=4, T=16, H=32, D=128, L=4096, HALF=64
// Inputs (setup_inputs order):
//   0: k_new  [B,T,H,D]  f32
//   1: v_new  [B,T,H,D]  f32
//   2: cos    [L,HALF]   f32
//   3: sin    [L,HALF]   f32
//   4: cache_k [B,L,H,D] f32
//   5: cache_v [B,L,H,D] f32
//   6: positions [B,T]   i32
// Output: [2, B, L, H, D] f32 — stack(out_k, out_v)

#define B 4
#define T 16
#define H 32
#define D 128
#define L 4096
#define HALF 64

typedef float f32x4 __attribute__((ext_vector_type(4)));

// ---------------------------------------------------------------------------
// Batched copy, depth 8 (R5's winning structure) + nontemporal hints
// (R6/R7 A/B showed nt = +3.6% at depth 16; depth 16 itself was the
// regression). Each block owns a contiguous 2048-float4 (32 KiB) chunk of
// the flat [cache_k ; cache_v] space: 8 independent nt loads (128 B in
// flight/thread), then 8 nt stores — long unidirectional bursts, no LLC
// thrash from the 1 GB zero-reuse stream.
// Chunks never straddle the k/v boundary (n4 % 2048 == 0).
// ---------------------------------------------------------------------------
#define PER_THREAD 8
#define CHUNK (256 * PER_THREAD)   // 2048 float4s = 32 KiB per block

__global__ __launch_bounds__(256) void copy_caches_batched(
    const f32x4* __restrict__ cache_k,
    const f32x4* __restrict__ cache_v,
    f32x4* __restrict__ out,
    long n4) {
    const long flat0 = (long)blockIdx.x * CHUNK;           // block's first float4
    const bool second = flat0 >= n4;                        // block-uniform
    const f32x4* __restrict__ src = second ? cache_v : cache_k;
    const long srcoff = second ? (flat0 - n4) : flat0;

    const int t = threadIdx.x;
    f32x4 r[PER_THREAD];
#pragma unroll
    for (int j = 0; j < PER_THREAD; ++j)
        r[j] = __builtin_nontemporal_load(src + srcoff + t + j * 256);
#pragma unroll
    for (int j = 0; j < PER_THREAD; ++j)
        __builtin_nontemporal_store(r[j], out + flat0 + t + j * 256);
}

// ---------------------------------------------------------------------------
// RoPE-rotate k_new and scatter k_rot / v_new into the output at the row
// given by positions[b,t]. One thread per interleaved pair. Runs AFTER the
// bulk copy on the same stream, overwriting the 64 target rows.
// ---------------------------------------------------------------------------
__global__ void rope_scatter(const float* __restrict__ k_new,
                             const float* __restrict__ v_new,
                             const float* __restrict__ cos_t,
                             const float* __restrict__ sin_t,
                             const int* __restrict__ positions,
                             float* __restrict__ out_k,
                             float* __restrict__ out_v) {
    int idx = blockIdx.x * blockDim.x + threadIdx.x;   // [0, B*T*H*HALF)
    int p  = idx & (HALF - 1);          // pair index within head dim
    int h  = (idx >> 6) & (H - 1);      // head
    int bt = idx >> 11;                 // b*T + t
    int b  = bt >> 4;                   // /T (T=16)

    int pos = positions[bt];

    const float2 kv = *(const float2*)(k_new + (size_t)idx * 2);
    const float2 vv = *(const float2*)(v_new + (size_t)idx * 2);
    float c = cos_t[pos * HALF + p];
    float s = sin_t[pos * HALF + p];

    float2 kr;
    kr.x = kv.x * c - kv.y * s;
    kr.y = kv.x * s + kv.y * c;

    size_t dst = (((size_t)b * L + pos) * H + h) * (size_t)D + 2 * (size_t)p;
    *(float2*)(out_k + dst) = kr;
    *(float2*)(out_v + dst) = vv;
}

extern "C" void kernel_launch(void* const* d_in, const int* in_sizes, int n_in,
                              void* d_out, int out_size, void* d_ws, size_t ws_size,
                              hipStream_t stream) {
    const float* k_new  = (const float*)d_in[0];
    const float* v_new  = (const float*)d_in[1];
    const float* cos_t  = (const float*)d_in[2];
    const float* sin_t  = (const float*)d_in[3];
    const f32x4* ck     = (const f32x4*)d_in[4];
    const f32x4* cv     = (const f32x4*)d_in[5];
    const int* positions = (const int*)d_in[6];

    float* out = (float*)d_out;
    const long cache_elems = (long)B * L * H * D;   // 67,108,864 floats
    const long n4 = cache_elems / 4;                // 16,777,216 float4s per cache

    // 2 * n4 / CHUNK = 16384 blocks, 256 threads, 8 float4s each, one shot.
    const int nblocks = (int)(2 * n4 / CHUNK);
    copy_caches_batched<<<nblocks, 256, 0, stream>>>(ck, cv, (f32x4*)out, n4);

    // Scatter: B*T*H*HALF = 131072 threads -> 512 blocks x 256.
    const int n_pairs = B * T * H * HALF;
    rope_scatter<<<n_pairs / 256, 256, 0, stream>>>(
        k_new, v_new, cos_t, sin_t, positions,
        out, out + cache_elems);
}